// Round 6
// baseline (109.893 us; speedup 1.0000x reference)
//
#include <hip/hip_runtime.h>
#include <math.h>

// KDE log-density: out[i] = log(1e-8 + (1/N) * sum_j exp(t1 - 50*||xe_i - xb_j||^2))
// N = 16384, D = 16, fp32 in/out.
//
// Round 6: R5 core (MFMA tile-screen + monotone atomicMin fusion) with a
// register-cached-A restructure of kde_main. R5's kde_main was L2-BW-bound:
// 8192 waves x 32KB B-reads = 256 MB of L2 traffic (7.4 us at 34.5 TB/s).
// Now each wave holds FOUR A-fragments (128 eval rows) and reuses every
// streamed B-fragment for 4 MFMAs -> B traffic 64 MB, issue-bound ~3 us.
// No LDS, no barriers, no device-scope fences (R4 lesson).
//
// Numerics unchanged: inputs pre-scaled by sqrt(100*log2e) before bf16 cast,
// d = 144.2695*dot + pe (pe rides the MFMA C operand); tile screened unless
// some d > THR - pb (terms < 2^-135 shift the output < 1e-37). Rare hit path
// atomicAdds S and atomicMins log(1e-8+(S_new)/N) raw-bits into out
// (all values negative => float-max == uint-min); kde_pre pre-writes
// out = log(1e-8), correct whenever S stays 0.

#define KDE_N 16384
#define KDE_D 16
#define G 4                    // A m-tiles register-cached per wave
#define THR (-135.0f)          // log2-domain underflow screen

typedef __attribute__((ext_vector_type(8)))  short   short8;
typedef __attribute__((ext_vector_type(16))) float   float16_t;

__device__ __forceinline__ unsigned short f32_to_bf16_rne(float f) {
    unsigned int u = __float_as_uint(f);
    unsigned int r = (u + 0x7FFFu + ((u >> 16) & 1u)) >> 16;
    return (unsigned short)r;
}

// ---- prologue: pe / (THR - pb), scaled bf16 casts, zero S, default out ----
__global__ void kde_pre(const float* __restrict__ xe, const float* __restrict__ xb,
                        float* __restrict__ S, float* __restrict__ pe,
                        float* __restrict__ pbthr, unsigned short* __restrict__ xe16,
                        unsigned short* __restrict__ xb16, float* __restrict__ out)
{
    const int t = blockIdx.x * blockDim.x + threadIdx.x;   // 0..32767
    const int row = t & (KDE_N - 1);
    const bool isB = t >= KDE_N;
    const float* src = (isB ? xb : xe) + (size_t)row * KDE_D;
    const float4* s4 = (const float4*)src;
    const float SQSC = 12.011224664550577f;   // sqrt(100*log2e)
    float q = 0.f;
    unsigned int w[8];
    #pragma unroll
    for (int k = 0; k < 4; ++k) {
        float4 v = s4[k];
        q += v.x*v.x + v.y*v.y + v.z*v.z + v.w*v.w;
        w[2*k+0] = (unsigned int)f32_to_bf16_rne(v.x * SQSC)
                 | ((unsigned int)f32_to_bf16_rne(v.y * SQSC) << 16);
        w[2*k+1] = (unsigned int)f32_to_bf16_rne(v.z * SQSC)
                 | ((unsigned int)f32_to_bf16_rne(v.w * SQSC) << 16);
    }
    unsigned short* dst = (isB ? xb16 : xe16) + (size_t)row * KDE_D;
    uint4* d4 = (uint4*)dst;
    d4[0] = make_uint4(w[0], w[1], w[2], w[3]);
    d4[1] = make_uint4(w[4], w[5], w[6], w[7]);
    const float T1L2E  = -17.8920067984f;       // log2e * t1
    const float C72    = 72.134752044447963f;   // 50 * log2e
    const float LOG1EM8 = -18.420680743952367f; // log(1e-8)
    if (!isB) { pe[row] = T1L2E - C72 * q; S[row] = 0.f; out[row] = LOG1EM8; }
    else      { pbthr[row] = THR + C72 * q; }   // THR - pb,  pb = -C72*b2
}

// ---- main: 4 register-cached A-tiles, streamed B; screen; rare exp path ----
__global__ __launch_bounds__(256, 4) void kde_main(
    const unsigned short* __restrict__ xe16, const unsigned short* __restrict__ xb16,
    const float* __restrict__ pe, const float* __restrict__ pbthr,
    float* __restrict__ S, float* __restrict__ out)
{
    const int lane = threadIdx.x & 63;
    const int wave = threadIdx.x >> 6;
    const int col  = lane & 31;   // A row / B col / C col
    const int half = lane >> 5;   // k-half for A/B frags; row-group/4 for C

    const int m0     = blockIdx.x * (32 * G);          // 128 rows per block
    const int jslice = blockIdx.y * 4 + wave;          // 0..63
    const int j0     = jslice * 256;                   // 8 B-tiles per wave

    // A fragments + C-operand pe vectors (C rows (r&3)+8*(r>>2)+4*half are
    // contiguous in groups of 4 -> float4 loads)
    short8    af[G];
    float16_t perv[G];
    #pragma unroll
    for (int g = 0; g < G; ++g) {
        const int mg = m0 + g * 32;
        af[g] = *(const short8*)(xe16 + (size_t)(mg + col) * KDE_D + half * 8);
        #pragma unroll
        for (int q = 0; q < 4; ++q) {
            float4 p = *(const float4*)(pe + mg + 8 * q + 4 * half);
            perv[g][4*q+0] = p.x; perv[g][4*q+1] = p.y;
            perv[g][4*q+2] = p.z; perv[g][4*q+3] = p.w;
        }
    }

    const float INVN = 1.0f / (float)KDE_N;

    auto screen = [&](const float16_t& d, float thrv, int mg) {
        float m1 = fmaxf(fmaxf(d[0],  d[1]),  d[2]);
        float m2 = fmaxf(fmaxf(d[3],  d[4]),  d[5]);
        float m3 = fmaxf(fmaxf(d[6],  d[7]),  d[8]);
        float m4 = fmaxf(fmaxf(d[9],  d[10]), d[11]);
        float m5 = fmaxf(fmaxf(d[12], d[13]), d[14]);
        float x  = fmaxf(fmaxf(m1, m2), m3);
        float y  = fmaxf(fmaxf(m4, m5), d[15]);
        float mx = fmaxf(x, y);
        if (__any(mx > thrv)) {
            const float pbv = THR - thrv;      // = pb[col]
            #pragma unroll
            for (int r = 0; r < 16; ++r) {
                float e = exp2f(d[r] + pbv);
                if (e != 0.f) {
                    const int row = mg + (r & 3) + 8 * (r >> 2) + 4 * half;
                    float old  = atomicAdd(&S[row], e);
                    float cand = logf(1e-8f + (old + e) * INVN);
                    // all cands negative: float-max == uint-min on raw bits
                    atomicMin((unsigned int*)&out[row], __float_as_uint(cand));
                }
            }
        }
    };

    const unsigned short* bp = xb16 + (size_t)(j0 + col) * KDE_D + half * 8;
    const float*          tp = pbthr + (j0 + col);
    short8 bf   = *(const short8*)bp;
    float  thrv = *tp;

    #pragma unroll
    for (int t = 0; t < 7; ++t) {
        bp += 32 * KDE_D;  tp += 32;
        const short8 bf_n  = *(const short8*)bp;   // prefetch next B-tile
        const float  thr_n = *tp;
        #pragma unroll
        for (int g = 0; g < G; ++g) {
            float16_t d = __builtin_amdgcn_mfma_f32_32x32x16_bf16(af[g], bf, perv[g], 0, 0, 0);
            screen(d, thrv, m0 + g * 32);
        }
        bf = bf_n; thrv = thr_n;
    }
    {   // peeled last B-tile (no prefetch)
        #pragma unroll
        for (int g = 0; g < G; ++g) {
            float16_t d = __builtin_amdgcn_mfma_f32_32x32x16_bf16(af[g], bf, perv[g], 0, 0, 0);
            screen(d, thrv, m0 + g * 32);
        }
    }
}

extern "C" void kernel_launch(void* const* d_in, const int* in_sizes, int n_in,
                              void* d_out, int out_size, void* d_ws, size_t ws_size,
                              hipStream_t stream)
{
    const float* xe = (const float*)d_in[0];  // x_eval [16384,16] fp32
    const float* xb = (const float*)d_in[1];  // x_base [16384,16] fp32
    float* out = (float*)d_out;

    // ws layout: S[16384] | pe[16384] | pbthr[16384] | xe16 | xb16
    float* S     = (float*)d_ws;
    float* pe    = S + KDE_N;
    float* pbthr = pe + KDE_N;
    unsigned short* xe16 = (unsigned short*)(pbthr + KDE_N);
    unsigned short* xb16 = xe16 + (size_t)KDE_N * KDE_D;

    kde_pre<<<(2 * KDE_N) / 256, 256, 0, stream>>>(xe, xb, S, pe, pbthr, xe16, xb16, out);
    dim3 grid(KDE_N / (32 * G), 16);   // (128, 16) = 2048 blocks
    kde_main<<<grid, 256, 0, stream>>>(xe16, xb16, pe, pbthr, S, out);
}